// Round 1
// baseline (504.694 us; speedup 1.0000x reference)
//
#include <hip/hip_runtime.h>
#include <hip/hip_bf16.h>

// Problem constants
#define B_    16
#define C_    512
#define HW_   1024
#define G_    32
#define CPG_  16      // channels per group
#define NH_   4
#define D_    128
#define EPS_  1e-5f
#define SCALE_ 0.08838834764831845f  // 1/sqrt(128)

typedef short bf16x8 __attribute__((ext_vector_type(8)));
typedef float f32x4  __attribute__((ext_vector_type(4)));

__device__ __forceinline__ bf16x8 ld8(const __hip_bfloat16* p) {
    return *reinterpret_cast<const bf16x8*>(p);
}

// ---------------------------------------------------------------- weights
__global__ __launch_bounds__(256) void convert_w(
    const float* __restrict__ wqkv, const float* __restrict__ wout,
    __hip_bfloat16* __restrict__ wqkv_bf, __hip_bfloat16* __restrict__ wout_bf) {
    int i = blockIdx.x * 256 + threadIdx.x;
    if (i < 3 * C_ * C_) wqkv_bf[i] = __float2bfloat16(wqkv[i]);
    if (i < C_ * C_)     wout_bf[i] = __float2bfloat16(wout[i]);
}

// ---------------------------------------------------------------- groupnorm
// one block per (b,g); writes xn transposed: xn_t[b][hw][c] (bf16)
__global__ __launch_bounds__(256) void gn_kernel(
    const float* __restrict__ x, const float* __restrict__ gnw,
    const float* __restrict__ gnb, __hip_bfloat16* __restrict__ xn_t) {
    const int b = blockIdx.x >> 5;
    const int g = blockIdx.x & 31;
    const float* xp = x + ((size_t)(b * C_ + g * CPG_)) * HW_;  // 16x1024 contiguous

    float s = 0.f, s2 = 0.f;
    const float4* xv = reinterpret_cast<const float4*>(xp);
    #pragma unroll
    for (int t = 0; t < 16; ++t) {
        float4 v = xv[threadIdx.x + t * 256];
        s  += v.x + v.y + v.z + v.w;
        s2 += v.x * v.x + v.y * v.y + v.z * v.z + v.w * v.w;
    }
    #pragma unroll
    for (int off = 32; off > 0; off >>= 1) {
        s  += __shfl_down(s,  off, 64);
        s2 += __shfl_down(s2, off, 64);
    }
    __shared__ float ss[4], ss2[4];
    if ((threadIdx.x & 63) == 0) { ss[threadIdx.x >> 6] = s; ss2[threadIdx.x >> 6] = s2; }
    __syncthreads();
    s = ss[0] + ss[1] + ss[2] + ss[3];
    s2 = ss2[0] + ss2[1] + ss2[2] + ss2[3];
    const float mean = s * (1.f / 16384.f);
    const float inv  = rsqrtf(fmaxf(s2 * (1.f / 16384.f) - mean * mean, 0.f) + EPS_);

    for (int t = threadIdx.x; t < 16384; t += 256) {
        int hw = t >> 4, cc = t & 15;
        int ch = g * CPG_ + cc;
        float y = (xp[cc * HW_ + hw] - mean) * inv * gnw[ch] + gnb[ch];
        xn_t[((size_t)b * HW_ + hw) * C_ + ch] = __float2bfloat16(y);
    }
}

// ---------------------------------------------------------------- QKV GEMM
// per batch: qkv[o][i] = sum_c W[o][c] * xn_t[i][c]   (o in [0,1536), i in [0,1024))
// q,k written transposed [b][h][i][d] (q pre-scaled); v written [b][h][d][i]
__global__ __launch_bounds__(256) void qkv_gemm(
    const __hip_bfloat16* __restrict__ W, const __hip_bfloat16* __restrict__ xn_t,
    __hip_bfloat16* __restrict__ q_t, __hip_bfloat16* __restrict__ k_t,
    __hip_bfloat16* __restrict__ v_s) {
    const int b = blockIdx.z;
    const int w = threadIdx.x >> 6;
    const int lane = threadIdx.x & 63;
    const int l16 = lane & 15, lg = lane >> 4;
    const int o0 = blockIdx.x * 128 + (w >> 1) * 64;
    const int i0 = blockIdx.y * 128 + (w & 1) * 64;
    const __hip_bfloat16* xb = xn_t + (size_t)b * HW_ * C_;

    f32x4 acc[4][4];
    const f32x4 z = {0.f, 0.f, 0.f, 0.f};
    #pragma unroll
    for (int m = 0; m < 4; ++m)
        #pragma unroll
        for (int n = 0; n < 4; ++n) acc[m][n] = z;

    for (int kk = 0; kk < C_; kk += 32) {
        bf16x8 af[4], bfr[4];
        #pragma unroll
        for (int m = 0; m < 4; ++m)
            af[m] = ld8(W + (size_t)(o0 + m * 16 + l16) * C_ + kk + lg * 8);
        #pragma unroll
        for (int n = 0; n < 4; ++n)
            bfr[n] = ld8(xb + (size_t)(i0 + n * 16 + l16) * C_ + kk + lg * 8);
        #pragma unroll
        for (int m = 0; m < 4; ++m)
            #pragma unroll
            for (int n = 0; n < 4; ++n)
                acc[m][n] = __builtin_amdgcn_mfma_f32_16x16x32_bf16(af[m], bfr[n], acc[m][n], 0, 0, 0);
    }

    #pragma unroll
    for (int m = 0; m < 4; ++m) {
        #pragma unroll
        for (int r = 0; r < 4; ++r) {
            const int o = o0 + m * 16 + lg * 4 + r;
            #pragma unroll
            for (int n = 0; n < 4; ++n) {
                const int i = i0 + n * 16 + l16;
                float v = acc[m][n][r];
                if (o < C_) {
                    int hd = o >> 7, dd = o & 127;
                    q_t[((size_t)(b * NH_ + hd) * HW_ + i) * D_ + dd] = __float2bfloat16(v * SCALE_);
                } else if (o < 2 * C_) {
                    int c = o - C_; int hd = c >> 7, dd = c & 127;
                    k_t[((size_t)(b * NH_ + hd) * HW_ + i) * D_ + dd] = __float2bfloat16(v);
                } else {
                    int c = o - 2 * C_; int hd = c >> 7, dd = c & 127;
                    v_s[((size_t)(b * NH_ + hd) * D_ + dd) * HW_ + i] = __float2bfloat16(v);
                }
            }
        }
    }
}

// ---------------------------------------------------------------- attention
// grid (i-tile, head, batch); 8 waves, each owns 16 query rows; flash-style.
__global__ __launch_bounds__(512) void attn_kernel(
    const __hip_bfloat16* __restrict__ q_t, const __hip_bfloat16* __restrict__ k_t,
    const __hip_bfloat16* __restrict__ v_s, __hip_bfloat16* __restrict__ at) {
    const int it = blockIdx.x;
    const int h  = blockIdx.y;
    const int b  = blockIdx.z;
    const int w  = threadIdx.x >> 6;
    const int lane = threadIdx.x & 63;
    const int l16 = lane & 15, lg = lane >> 4;
    const size_t bh = (size_t)b * NH_ + h;
    const __hip_bfloat16* qp = q_t + bh * HW_ * D_;
    const __hip_bfloat16* kp = k_t + bh * HW_ * D_;
    const __hip_bfloat16* vp = v_s + bh * D_ * HW_;
    const int i0 = it * 128 + w * 16;

    __shared__ __align__(16) __hip_bfloat16 P_lds[8][16][72];

    bf16x8 aq[4];
    #pragma unroll
    for (int kd = 0; kd < 4; ++kd)
        aq[kd] = ld8(qp + (size_t)(i0 + l16) * D_ + kd * 32 + lg * 8);

    f32x4 accO[8];
    const f32x4 z = {0.f, 0.f, 0.f, 0.f};
    #pragma unroll
    for (int t = 0; t < 8; ++t) accO[t] = z;
    float mrow[4] = {-INFINITY, -INFINITY, -INFINITY, -INFINITY};
    float lrow[4] = {0.f, 0.f, 0.f, 0.f};

    for (int jb = 0; jb < 16; ++jb) {
        const int j0 = jb * 64;
        f32x4 s[4];
        #pragma unroll
        for (int jt = 0; jt < 4; ++jt) s[jt] = z;
        #pragma unroll
        for (int jt = 0; jt < 4; ++jt) {
            #pragma unroll
            for (int kd = 0; kd < 4; ++kd) {
                bf16x8 bk = ld8(kp + (size_t)(j0 + jt * 16 + l16) * D_ + kd * 32 + lg * 8);
                s[jt] = __builtin_amdgcn_mfma_f32_16x16x32_bf16(aq[kd], bk, s[jt], 0, 0, 0);
            }
        }
        // online softmax (rows live in s[jt][r], cols across the 16-lane group)
        float p[4][4], alpha[4];
        #pragma unroll
        for (int r = 0; r < 4; ++r) {
            float mx = fmaxf(fmaxf(s[0][r], s[1][r]), fmaxf(s[2][r], s[3][r]));
            #pragma unroll
            for (int off = 1; off < 16; off <<= 1) mx = fmaxf(mx, __shfl_xor(mx, off, 64));
            float mnew = fmaxf(mrow[r], mx);
            alpha[r] = __expf(mrow[r] - mnew);
            mrow[r] = mnew;
            float sm = 0.f;
            #pragma unroll
            for (int jt = 0; jt < 4; ++jt) { p[jt][r] = __expf(s[jt][r] - mnew); sm += p[jt][r]; }
            #pragma unroll
            for (int off = 1; off < 16; off <<= 1) sm += __shfl_xor(sm, off, 64);
            lrow[r] = lrow[r] * alpha[r] + sm;
        }
        {
            const f32x4 a4 = {alpha[0], alpha[1], alpha[2], alpha[3]};
            #pragma unroll
            for (int t = 0; t < 8; ++t) accO[t] *= a4;
        }
        // P -> LDS (D-layout scatter), then re-read as A-fragments
        #pragma unroll
        for (int jt = 0; jt < 4; ++jt)
            #pragma unroll
            for (int r = 0; r < 4; ++r)
                P_lds[w][lg * 4 + r][jt * 16 + l16] = __float2bfloat16(p[jt][r]);
        __syncthreads();
        #pragma unroll
        for (int ks = 0; ks < 2; ++ks) {
            bf16x8 pa = ld8(&P_lds[w][l16][ks * 32 + lg * 8]);
            #pragma unroll
            for (int dt = 0; dt < 8; ++dt) {
                bf16x8 bv = ld8(vp + (size_t)(dt * 16 + l16) * HW_ + j0 + ks * 32 + lg * 8);
                accO[dt] = __builtin_amdgcn_mfma_f32_16x16x32_bf16(pa, bv, accO[dt], 0, 0, 0);
            }
        }
        __syncthreads();
    }

    #pragma unroll
    for (int r = 0; r < 4; ++r) {
        float rl = 1.f / lrow[r];
        int i = i0 + lg * 4 + r;
        #pragma unroll
        for (int dt = 0; dt < 8; ++dt)
            at[((size_t)b * HW_ + i) * C_ + h * D_ + dt * 16 + l16] =
                __float2bfloat16(accO[dt][r] * rl);
    }
}

// ---------------------------------------------------------------- out GEMM + bias + residual
__global__ __launch_bounds__(256) void out_gemm(
    const __hip_bfloat16* __restrict__ W, const __hip_bfloat16* __restrict__ at,
    const float* __restrict__ b_out, const float* __restrict__ x,
    float* __restrict__ out) {
    const int b = blockIdx.z;
    const int w = threadIdx.x >> 6;
    const int lane = threadIdx.x & 63;
    const int l16 = lane & 15, lg = lane >> 4;
    const int o0 = blockIdx.x * 128 + (w >> 1) * 64;
    const int i0 = blockIdx.y * 128 + (w & 1) * 64;
    const __hip_bfloat16* ab = at + (size_t)b * HW_ * C_;

    f32x4 acc[4][4];
    const f32x4 z = {0.f, 0.f, 0.f, 0.f};
    #pragma unroll
    for (int m = 0; m < 4; ++m)
        #pragma unroll
        for (int n = 0; n < 4; ++n) acc[m][n] = z;

    for (int kk = 0; kk < C_; kk += 32) {
        bf16x8 af[4], bfr[4];
        #pragma unroll
        for (int m = 0; m < 4; ++m)
            af[m] = ld8(W + (size_t)(o0 + m * 16 + l16) * C_ + kk + lg * 8);
        #pragma unroll
        for (int n = 0; n < 4; ++n)
            bfr[n] = ld8(ab + (size_t)(i0 + n * 16 + l16) * C_ + kk + lg * 8);
        #pragma unroll
        for (int m = 0; m < 4; ++m)
            #pragma unroll
            for (int n = 0; n < 4; ++n)
                acc[m][n] = __builtin_amdgcn_mfma_f32_16x16x32_bf16(af[m], bfr[n], acc[m][n], 0, 0, 0);
    }

    #pragma unroll
    for (int m = 0; m < 4; ++m) {
        #pragma unroll
        for (int r = 0; r < 4; ++r) {
            const int o = o0 + m * 16 + lg * 4 + r;
            const float bo = b_out[o];
            #pragma unroll
            for (int n = 0; n < 4; ++n) {
                const int i = i0 + n * 16 + l16;
                const size_t idx = ((size_t)(b * C_ + o)) * HW_ + i;
                out[idx] = acc[m][n][r] + bo + x[idx];
            }
        }
    }
}

// ---------------------------------------------------------------- launch
extern "C" void kernel_launch(void* const* d_in, const int* in_sizes, int n_in,
                              void* d_out, int out_size, void* d_ws, size_t ws_size,
                              hipStream_t stream) {
    (void)in_sizes; (void)n_in; (void)out_size; (void)ws_size;
    const float* x     = (const float*)d_in[0];
    const float* gn_w  = (const float*)d_in[1];
    const float* gn_b  = (const float*)d_in[2];
    const float* w_qkv = (const float*)d_in[3];
    const float* w_out = (const float*)d_in[4];
    const float* b_out = (const float*)d_in[5];
    float* out = (float*)d_out;

    char* ws = (char*)d_ws;
    size_t off = 0;
    auto alloc = [&](size_t bytes) { void* p = ws + off; off += (bytes + 255) & ~255ULL; return p; };
    __hip_bfloat16* wqkv_bf = (__hip_bfloat16*)alloc((size_t)3 * C_ * C_ * 2);
    __hip_bfloat16* wout_bf = (__hip_bfloat16*)alloc((size_t)C_ * C_ * 2);
    __hip_bfloat16* xn_t    = (__hip_bfloat16*)alloc((size_t)B_ * HW_ * C_ * 2);
    __hip_bfloat16* q_t     = (__hip_bfloat16*)alloc((size_t)B_ * HW_ * C_ * 2);
    __hip_bfloat16* k_t     = (__hip_bfloat16*)alloc((size_t)B_ * HW_ * C_ * 2);
    __hip_bfloat16* v_s     = (__hip_bfloat16*)alloc((size_t)B_ * HW_ * C_ * 2);
    __hip_bfloat16* at      = xn_t;  // alias: xn_t dead after qkv_gemm

    convert_w<<<3072, 256, 0, stream>>>(w_qkv, w_out, wqkv_bf, wout_bf);
    gn_kernel<<<512, 256, 0, stream>>>(x, gn_w, gn_b, xn_t);
    qkv_gemm<<<dim3(12, 8, 16), 256, 0, stream>>>(wqkv_bf, xn_t, q_t, k_t, v_s);
    attn_kernel<<<dim3(8, 4, 16), 512, 0, stream>>>(q_t, k_t, v_s, at);
    out_gemm<<<dim3(4, 8, 16), 256, 0, stream>>>(wout_bf, at, b_out, x, out);
}

// Round 2
// 432.216 us; speedup vs baseline: 1.1677x; 1.1677x over previous
//
#include <hip/hip_runtime.h>
#include <hip/hip_bf16.h>

// Problem constants
#define B_    16
#define C_    512
#define HW_   1024
#define G_    32
#define CPG_  16      // channels per group
#define NH_   4
#define D_    128
#define EPS_  1e-5f
#define SCALE_ 0.08838834764831845f  // 1/sqrt(128)

typedef short bf16x8 __attribute__((ext_vector_type(8)));
typedef short bf16x4 __attribute__((ext_vector_type(4)));
typedef float f32x4  __attribute__((ext_vector_type(4)));

__device__ __forceinline__ bf16x8 ld8(const __hip_bfloat16* p) {
    return *reinterpret_cast<const bf16x8*>(p);
}

// ---------------------------------------------------------------- weights
__global__ __launch_bounds__(256) void convert_w(
    const float* __restrict__ wqkv, const float* __restrict__ wout,
    __hip_bfloat16* __restrict__ wqkv_bf, __hip_bfloat16* __restrict__ wout_bf) {
    const int i = (blockIdx.x * 256 + threadIdx.x) * 4;
    if (i < 3 * C_ * C_) {
        float4 v = *reinterpret_cast<const float4*>(wqkv + i);
        union { bf16x4 s; __hip_bfloat16 h[4]; } u;
        u.h[0] = __float2bfloat16(v.x); u.h[1] = __float2bfloat16(v.y);
        u.h[2] = __float2bfloat16(v.z); u.h[3] = __float2bfloat16(v.w);
        *reinterpret_cast<bf16x4*>(wqkv_bf + i) = u.s;
    }
    if (i < C_ * C_) {
        float4 v = *reinterpret_cast<const float4*>(wout + i);
        union { bf16x4 s; __hip_bfloat16 h[4]; } u;
        u.h[0] = __float2bfloat16(v.x); u.h[1] = __float2bfloat16(v.y);
        u.h[2] = __float2bfloat16(v.z); u.h[3] = __float2bfloat16(v.w);
        *reinterpret_cast<bf16x4*>(wout_bf + i) = u.s;
    }
}

// ---------------------------------------------------------------- groupnorm
// one block per (b,g); writes xn transposed: xn_t[b][hw][c] (bf16)
__global__ __launch_bounds__(256) void gn_kernel(
    const float* __restrict__ x, const float* __restrict__ gnw,
    const float* __restrict__ gnb, __hip_bfloat16* __restrict__ xn_t) {
    const int b = blockIdx.x >> 5;
    const int g = blockIdx.x & 31;
    const float* xp = x + ((size_t)(b * C_ + g * CPG_)) * HW_;  // 16x1024 contiguous

    float s = 0.f, s2 = 0.f;
    const float4* xv = reinterpret_cast<const float4*>(xp);
    #pragma unroll
    for (int t = 0; t < 16; ++t) {
        float4 v = xv[threadIdx.x + t * 256];
        s  += v.x + v.y + v.z + v.w;
        s2 += v.x * v.x + v.y * v.y + v.z * v.z + v.w * v.w;
    }
    #pragma unroll
    for (int off = 32; off > 0; off >>= 1) {
        s  += __shfl_down(s,  off, 64);
        s2 += __shfl_down(s2, off, 64);
    }
    __shared__ float ss[4], ss2[4];
    if ((threadIdx.x & 63) == 0) { ss[threadIdx.x >> 6] = s; ss2[threadIdx.x >> 6] = s2; }
    __syncthreads();
    s = ss[0] + ss[1] + ss[2] + ss[3];
    s2 = ss2[0] + ss2[1] + ss2[2] + ss2[3];
    const float mean = s * (1.f / 16384.f);
    const float inv  = rsqrtf(fmaxf(s2 * (1.f / 16384.f) - mean * mean, 0.f) + EPS_);

    // per-channel affine folded: y = v*a[cc] + bb[cc]
    float a[16], bb[16];
    #pragma unroll
    for (int cc = 0; cc < 16; ++cc) {
        float w = gnw[g * CPG_ + cc];
        a[cc] = inv * w;
        bb[cc] = gnb[g * CPG_ + cc] - mean * inv * w;
    }

    for (int hw = threadIdx.x; hw < HW_; hw += 256) {
        union { bf16x8 v; __hip_bfloat16 h[8]; } u0, u1;
        #pragma unroll
        for (int cc = 0; cc < 8; ++cc)
            u0.h[cc] = __float2bfloat16(xp[cc * HW_ + hw] * a[cc] + bb[cc]);
        #pragma unroll
        for (int cc = 8; cc < 16; ++cc)
            u1.h[cc - 8] = __float2bfloat16(xp[cc * HW_ + hw] * a[cc] + bb[cc]);
        __hip_bfloat16* dst = xn_t + ((size_t)(b * HW_ + hw)) * C_ + g * CPG_;
        *reinterpret_cast<bf16x8*>(dst) = u0.v;
        *reinterpret_cast<bf16x8*>(dst + 8) = u1.v;
    }
}

// ---------------------------------------------------------------- QKV GEMM
__global__ __launch_bounds__(256) void qkv_gemm(
    const __hip_bfloat16* __restrict__ W, const __hip_bfloat16* __restrict__ xn_t,
    __hip_bfloat16* __restrict__ q_t, __hip_bfloat16* __restrict__ k_t,
    __hip_bfloat16* __restrict__ v_s) {
    const int b = blockIdx.z;
    const int w = threadIdx.x >> 6;
    const int lane = threadIdx.x & 63;
    const int l16 = lane & 15, lg = lane >> 4;
    const int o0 = blockIdx.x * 128 + (w >> 1) * 64;
    const int i0 = blockIdx.y * 128 + (w & 1) * 64;
    const __hip_bfloat16* xb = xn_t + (size_t)b * HW_ * C_;

    f32x4 acc[4][4];
    const f32x4 z = {0.f, 0.f, 0.f, 0.f};
    #pragma unroll
    for (int m = 0; m < 4; ++m)
        #pragma unroll
        for (int n = 0; n < 4; ++n) acc[m][n] = z;

    for (int kk = 0; kk < C_; kk += 32) {
        bf16x8 af[4], bfr[4];
        #pragma unroll
        for (int m = 0; m < 4; ++m)
            af[m] = ld8(W + (size_t)(o0 + m * 16 + l16) * C_ + kk + lg * 8);
        #pragma unroll
        for (int n = 0; n < 4; ++n)
            bfr[n] = ld8(xb + (size_t)(i0 + n * 16 + l16) * C_ + kk + lg * 8);
        #pragma unroll
        for (int m = 0; m < 4; ++m)
            #pragma unroll
            for (int n = 0; n < 4; ++n)
                acc[m][n] = __builtin_amdgcn_mfma_f32_16x16x32_bf16(af[m], bfr[n], acc[m][n], 0, 0, 0);
    }

    #pragma unroll
    for (int m = 0; m < 4; ++m) {
        #pragma unroll
        for (int r = 0; r < 4; ++r) {
            const int o = o0 + m * 16 + lg * 4 + r;
            #pragma unroll
            for (int n = 0; n < 4; ++n) {
                const int i = i0 + n * 16 + l16;
                float v = acc[m][n][r];
                if (o < C_) {
                    int hd = o >> 7, dd = o & 127;
                    q_t[((size_t)(b * NH_ + hd) * HW_ + i) * D_ + dd] = __float2bfloat16(v * SCALE_);
                } else if (o < 2 * C_) {
                    int c = o - C_; int hd = c >> 7, dd = c & 127;
                    k_t[((size_t)(b * NH_ + hd) * HW_ + i) * D_ + dd] = __float2bfloat16(v);
                } else {
                    int c = o - 2 * C_; int hd = c >> 7, dd = c & 127;
                    v_s[((size_t)(b * NH_ + hd) * D_ + dd) * HW_ + i] = __float2bfloat16(v);
                }
            }
        }
    }
}

// ---------------------------------------------------------------- attention
// grid (i-tile, head, batch); 8 independent waves, each owns 16 query rows.
// NO __syncthreads: each wave touches only its own P_lds[w] slice, and LDS
// ops within a wave are program-ordered.
__global__ __launch_bounds__(512, 4) void attn_kernel(
    const __hip_bfloat16* __restrict__ q_t, const __hip_bfloat16* __restrict__ k_t,
    const __hip_bfloat16* __restrict__ v_s, __hip_bfloat16* __restrict__ at) {
    const int it = blockIdx.x;
    const int h  = blockIdx.y;
    const int b  = blockIdx.z;
    const int w  = threadIdx.x >> 6;
    const int lane = threadIdx.x & 63;
    const int l16 = lane & 15, lg = lane >> 4;
    const size_t bh = (size_t)b * NH_ + h;
    const __hip_bfloat16* qp = q_t + bh * HW_ * D_;
    const __hip_bfloat16* kp = k_t + bh * HW_ * D_;
    const __hip_bfloat16* vp = v_s + bh * D_ * HW_;
    const int i0 = it * 128 + w * 16;

    __shared__ __align__(16) __hip_bfloat16 P_lds[8][16][72];

    bf16x8 aq[4];
    #pragma unroll
    for (int kd = 0; kd < 4; ++kd)
        aq[kd] = ld8(qp + (size_t)(i0 + l16) * D_ + kd * 32 + lg * 8);

    f32x4 accO[8];
    const f32x4 z = {0.f, 0.f, 0.f, 0.f};
    #pragma unroll
    for (int t = 0; t < 8; ++t) accO[t] = z;
    float mrow[4] = {-INFINITY, -INFINITY, -INFINITY, -INFINITY};
    float lrow[4] = {0.f, 0.f, 0.f, 0.f};

    for (int jb = 0; jb < 16; ++jb) {
        const int j0 = jb * 64;
        // ---- QK^T: all 16 K fragments issued up front (max MLP in flight)
        bf16x8 bk[4][4];
        #pragma unroll
        for (int jt = 0; jt < 4; ++jt)
            #pragma unroll
            for (int kd = 0; kd < 4; ++kd)
                bk[jt][kd] = ld8(kp + (size_t)(j0 + jt * 16 + l16) * D_ + kd * 32 + lg * 8);
        f32x4 s[4];
        #pragma unroll
        for (int jt = 0; jt < 4; ++jt) s[jt] = z;
        #pragma unroll
        for (int jt = 0; jt < 4; ++jt)
            #pragma unroll
            for (int kd = 0; kd < 4; ++kd)
                s[jt] = __builtin_amdgcn_mfma_f32_16x16x32_bf16(aq[kd], bk[jt][kd], s[jt], 0, 0, 0);

        // ---- prefetch V first half; latency hides under softmax
        bf16x8 bv0[8];
        #pragma unroll
        for (int dt = 0; dt < 8; ++dt)
            bv0[dt] = ld8(vp + (size_t)(dt * 16 + l16) * HW_ + j0 + lg * 8);

        // ---- online softmax (rows in s[jt][r], cols across 16-lane group)
        float p[4][4], alpha[4];
        #pragma unroll
        for (int r = 0; r < 4; ++r) {
            float mx = fmaxf(fmaxf(s[0][r], s[1][r]), fmaxf(s[2][r], s[3][r]));
            #pragma unroll
            for (int off = 1; off < 16; off <<= 1) mx = fmaxf(mx, __shfl_xor(mx, off, 64));
            float mnew = fmaxf(mrow[r], mx);
            alpha[r] = __expf(mrow[r] - mnew);
            mrow[r] = mnew;
            float sm = 0.f;
            #pragma unroll
            for (int jt = 0; jt < 4; ++jt) { p[jt][r] = __expf(s[jt][r] - mnew); sm += p[jt][r]; }
            #pragma unroll
            for (int off = 1; off < 16; off <<= 1) sm += __shfl_xor(sm, off, 64);
            lrow[r] = lrow[r] * alpha[r] + sm;
        }
        {
            const f32x4 a4 = {alpha[0], alpha[1], alpha[2], alpha[3]};
            #pragma unroll
            for (int t = 0; t < 8; ++t) accO[t] *= a4;
        }

        // ---- P -> wave-private LDS slice (re-layout into A-fragments)
        #pragma unroll
        for (int jt = 0; jt < 4; ++jt)
            #pragma unroll
            for (int r = 0; r < 4; ++r)
                P_lds[w][lg * 4 + r][jt * 16 + l16] = __float2bfloat16(p[jt][r]);

        // ---- prefetch V second half (latency hides under PV first half)
        bf16x8 bv1[8];
        #pragma unroll
        for (int dt = 0; dt < 8; ++dt)
            bv1[dt] = ld8(vp + (size_t)(dt * 16 + l16) * HW_ + j0 + 32 + lg * 8);

        bf16x8 pa0 = ld8(&P_lds[w][l16][lg * 8]);
        #pragma unroll
        for (int dt = 0; dt < 8; ++dt)
            accO[dt] = __builtin_amdgcn_mfma_f32_16x16x32_bf16(pa0, bv0[dt], accO[dt], 0, 0, 0);
        bf16x8 pa1 = ld8(&P_lds[w][l16][32 + lg * 8]);
        #pragma unroll
        for (int dt = 0; dt < 8; ++dt)
            accO[dt] = __builtin_amdgcn_mfma_f32_16x16x32_bf16(pa1, bv1[dt], accO[dt], 0, 0, 0);
    }

    #pragma unroll
    for (int r = 0; r < 4; ++r) {
        float rl = 1.f / lrow[r];
        int i = i0 + lg * 4 + r;
        #pragma unroll
        for (int dt = 0; dt < 8; ++dt)
            at[((size_t)b * HW_ + i) * C_ + h * D_ + dt * 16 + l16] =
                __float2bfloat16(accO[dt][r] * rl);
    }
}

// ---------------------------------------------------------------- out GEMM + bias + residual
__global__ __launch_bounds__(256) void out_gemm(
    const __hip_bfloat16* __restrict__ W, const __hip_bfloat16* __restrict__ at,
    const float* __restrict__ b_out, const float* __restrict__ x,
    float* __restrict__ out) {
    const int b = blockIdx.z;
    const int w = threadIdx.x >> 6;
    const int lane = threadIdx.x & 63;
    const int l16 = lane & 15, lg = lane >> 4;
    const int o0 = blockIdx.x * 128 + (w >> 1) * 64;
    const int i0 = blockIdx.y * 128 + (w & 1) * 64;
    const __hip_bfloat16* ab = at + (size_t)b * HW_ * C_;

    f32x4 acc[4][4];
    const f32x4 z = {0.f, 0.f, 0.f, 0.f};
    #pragma unroll
    for (int m = 0; m < 4; ++m)
        #pragma unroll
        for (int n = 0; n < 4; ++n) acc[m][n] = z;

    for (int kk = 0; kk < C_; kk += 32) {
        bf16x8 af[4], bfr[4];
        #pragma unroll
        for (int m = 0; m < 4; ++m)
            af[m] = ld8(W + (size_t)(o0 + m * 16 + l16) * C_ + kk + lg * 8);
        #pragma unroll
        for (int n = 0; n < 4; ++n)
            bfr[n] = ld8(ab + (size_t)(i0 + n * 16 + l16) * C_ + kk + lg * 8);
        #pragma unroll
        for (int m = 0; m < 4; ++m)
            #pragma unroll
            for (int n = 0; n < 4; ++n)
                acc[m][n] = __builtin_amdgcn_mfma_f32_16x16x32_bf16(af[m], bfr[n], acc[m][n], 0, 0, 0);
    }

    #pragma unroll
    for (int m = 0; m < 4; ++m) {
        #pragma unroll
        for (int r = 0; r < 4; ++r) {
            const int o = o0 + m * 16 + lg * 4 + r;
            const float bo = b_out[o];
            #pragma unroll
            for (int n = 0; n < 4; ++n) {
                const int i = i0 + n * 16 + l16;
                const size_t idx = ((size_t)(b * C_ + o)) * HW_ + i;
                out[idx] = acc[m][n][r] + bo + x[idx];
            }
        }
    }
}

// ---------------------------------------------------------------- launch
extern "C" void kernel_launch(void* const* d_in, const int* in_sizes, int n_in,
                              void* d_out, int out_size, void* d_ws, size_t ws_size,
                              hipStream_t stream) {
    (void)in_sizes; (void)n_in; (void)out_size; (void)ws_size;
    const float* x     = (const float*)d_in[0];
    const float* gn_w  = (const float*)d_in[1];
    const float* gn_b  = (const float*)d_in[2];
    const float* w_qkv = (const float*)d_in[3];
    const float* w_out = (const float*)d_in[4];
    const float* b_out = (const float*)d_in[5];
    float* out = (float*)d_out;

    char* ws = (char*)d_ws;
    size_t off = 0;
    auto alloc = [&](size_t bytes) { void* p = ws + off; off += (bytes + 255) & ~255ULL; return p; };
    __hip_bfloat16* wqkv_bf = (__hip_bfloat16*)alloc((size_t)3 * C_ * C_ * 2);
    __hip_bfloat16* wout_bf = (__hip_bfloat16*)alloc((size_t)C_ * C_ * 2);
    __hip_bfloat16* xn_t    = (__hip_bfloat16*)alloc((size_t)B_ * HW_ * C_ * 2);
    __hip_bfloat16* q_t     = (__hip_bfloat16*)alloc((size_t)B_ * HW_ * C_ * 2);
    __hip_bfloat16* k_t     = (__hip_bfloat16*)alloc((size_t)B_ * HW_ * C_ * 2);
    __hip_bfloat16* v_s     = (__hip_bfloat16*)alloc((size_t)B_ * HW_ * C_ * 2);
    __hip_bfloat16* at      = xn_t;  // alias: xn_t dead after qkv_gemm

    convert_w<<<768, 256, 0, stream>>>(w_qkv, w_out, wqkv_bf, wout_bf);
    gn_kernel<<<512, 256, 0, stream>>>(x, gn_w, gn_b, xn_t);
    qkv_gemm<<<dim3(12, 8, 16), 256, 0, stream>>>(wqkv_bf, xn_t, q_t, k_t, v_s);
    attn_kernel<<<dim3(8, 4, 16), 512, 0, stream>>>(q_t, k_t, v_s, at);
    out_gemm<<<dim3(4, 8, 16), 256, 0, stream>>>(wout_bf, at, b_out, x, out);
}

// Round 3
// 265.778 us; speedup vs baseline: 1.8989x; 1.6262x over previous
//
#include <hip/hip_runtime.h>
#include <hip/hip_bf16.h>

// Problem constants
#define B_    16
#define C_    512
#define HW_   1024
#define G_    32
#define CPG_  16      // channels per group
#define NH_   4
#define D_    128
#define EPS_  1e-5f
#define SCALE_ 0.08838834764831845f  // 1/sqrt(128)

typedef short bf16x8 __attribute__((ext_vector_type(8)));
typedef short bf16x4 __attribute__((ext_vector_type(4)));
typedef float f32x4  __attribute__((ext_vector_type(4)));

__device__ __forceinline__ bf16x8 ld8(const __hip_bfloat16* p) {
    return *reinterpret_cast<const bf16x8*>(p);
}

// ---------------------------------------------------------------- weights
__global__ __launch_bounds__(256) void convert_w(
    const float* __restrict__ wqkv, const float* __restrict__ wout,
    __hip_bfloat16* __restrict__ wqkv_bf, __hip_bfloat16* __restrict__ wout_bf) {
    const int i = (blockIdx.x * 256 + threadIdx.x) * 4;
    if (i < 3 * C_ * C_) {
        float4 v = *reinterpret_cast<const float4*>(wqkv + i);
        union { bf16x4 s; __hip_bfloat16 h[4]; } u;
        u.h[0] = __float2bfloat16(v.x); u.h[1] = __float2bfloat16(v.y);
        u.h[2] = __float2bfloat16(v.z); u.h[3] = __float2bfloat16(v.w);
        *reinterpret_cast<bf16x4*>(wqkv_bf + i) = u.s;
    }
    if (i < C_ * C_) {
        float4 v = *reinterpret_cast<const float4*>(wout + i);
        union { bf16x4 s; __hip_bfloat16 h[4]; } u;
        u.h[0] = __float2bfloat16(v.x); u.h[1] = __float2bfloat16(v.y);
        u.h[2] = __float2bfloat16(v.z); u.h[3] = __float2bfloat16(v.w);
        *reinterpret_cast<bf16x4*>(wout_bf + i) = u.s;
    }
}

// ---------------------------------------------------------------- groupnorm
__global__ __launch_bounds__(256) void gn_kernel(
    const float* __restrict__ x, const float* __restrict__ gnw,
    const float* __restrict__ gnb, __hip_bfloat16* __restrict__ xn_t) {
    const int b = blockIdx.x >> 5;
    const int g = blockIdx.x & 31;
    const float* xp = x + ((size_t)(b * C_ + g * CPG_)) * HW_;  // 16x1024 contiguous

    float s = 0.f, s2 = 0.f;
    const float4* xv = reinterpret_cast<const float4*>(xp);
    #pragma unroll
    for (int t = 0; t < 16; ++t) {
        float4 v = xv[threadIdx.x + t * 256];
        s  += v.x + v.y + v.z + v.w;
        s2 += v.x * v.x + v.y * v.y + v.z * v.z + v.w * v.w;
    }
    #pragma unroll
    for (int off = 32; off > 0; off >>= 1) {
        s  += __shfl_down(s,  off, 64);
        s2 += __shfl_down(s2, off, 64);
    }
    __shared__ float ss[4], ss2[4];
    if ((threadIdx.x & 63) == 0) { ss[threadIdx.x >> 6] = s; ss2[threadIdx.x >> 6] = s2; }
    __syncthreads();
    s = ss[0] + ss[1] + ss[2] + ss[3];
    s2 = ss2[0] + ss2[1] + ss2[2] + ss2[3];
    const float mean = s * (1.f / 16384.f);
    const float inv  = rsqrtf(fmaxf(s2 * (1.f / 16384.f) - mean * mean, 0.f) + EPS_);

    float a[16], bb[16];
    #pragma unroll
    for (int cc = 0; cc < 16; ++cc) {
        float w = gnw[g * CPG_ + cc];
        a[cc] = inv * w;
        bb[cc] = gnb[g * CPG_ + cc] - mean * inv * w;
    }

    for (int hw = threadIdx.x; hw < HW_; hw += 256) {
        union { bf16x8 v; __hip_bfloat16 h[8]; } u0, u1;
        #pragma unroll
        for (int cc = 0; cc < 8; ++cc)
            u0.h[cc] = __float2bfloat16(xp[cc * HW_ + hw] * a[cc] + bb[cc]);
        #pragma unroll
        for (int cc = 8; cc < 16; ++cc)
            u1.h[cc - 8] = __float2bfloat16(xp[cc * HW_ + hw] * a[cc] + bb[cc]);
        __hip_bfloat16* dst = xn_t + ((size_t)(b * HW_ + hw)) * C_ + g * CPG_;
        *reinterpret_cast<bf16x8*>(dst) = u0.v;
        *reinterpret_cast<bf16x8*>(dst + 8) = u1.v;
    }
}

// ---------------------------------------------------------------- QKV GEMM
__global__ __launch_bounds__(256) void qkv_gemm(
    const __hip_bfloat16* __restrict__ W, const __hip_bfloat16* __restrict__ xn_t,
    __hip_bfloat16* __restrict__ q_t, __hip_bfloat16* __restrict__ k_t,
    __hip_bfloat16* __restrict__ v_s) {
    const int b = blockIdx.z;
    const int w = threadIdx.x >> 6;
    const int lane = threadIdx.x & 63;
    const int l16 = lane & 15, lg = lane >> 4;
    const int o0 = blockIdx.x * 128 + (w >> 1) * 64;
    const int i0 = blockIdx.y * 128 + (w & 1) * 64;
    const __hip_bfloat16* xb = xn_t + (size_t)b * HW_ * C_;

    f32x4 acc[4][4];
    const f32x4 z = {0.f, 0.f, 0.f, 0.f};
    #pragma unroll
    for (int m = 0; m < 4; ++m)
        #pragma unroll
        for (int n = 0; n < 4; ++n) acc[m][n] = z;

    for (int kk = 0; kk < C_; kk += 32) {
        bf16x8 af[4], bfr[4];
        #pragma unroll
        for (int m = 0; m < 4; ++m)
            af[m] = ld8(W + (size_t)(o0 + m * 16 + l16) * C_ + kk + lg * 8);
        #pragma unroll
        for (int n = 0; n < 4; ++n)
            bfr[n] = ld8(xb + (size_t)(i0 + n * 16 + l16) * C_ + kk + lg * 8);
        #pragma unroll
        for (int m = 0; m < 4; ++m)
            #pragma unroll
            for (int n = 0; n < 4; ++n)
                acc[m][n] = __builtin_amdgcn_mfma_f32_16x16x32_bf16(af[m], bfr[n], acc[m][n], 0, 0, 0);
    }

    #pragma unroll
    for (int m = 0; m < 4; ++m) {
        #pragma unroll
        for (int r = 0; r < 4; ++r) {
            const int o = o0 + m * 16 + lg * 4 + r;
            #pragma unroll
            for (int n = 0; n < 4; ++n) {
                const int i = i0 + n * 16 + l16;
                float v = acc[m][n][r];
                if (o < C_) {
                    int hd = o >> 7, dd = o & 127;
                    q_t[((size_t)(b * NH_ + hd) * HW_ + i) * D_ + dd] = __float2bfloat16(v * SCALE_);
                } else if (o < 2 * C_) {
                    int c = o - C_; int hd = c >> 7, dd = c & 127;
                    k_t[((size_t)(b * NH_ + hd) * HW_ + i) * D_ + dd] = __float2bfloat16(v);
                } else {
                    int c = o - 2 * C_; int hd = c >> 7, dd = c & 127;
                    v_s[((size_t)(b * NH_ + hd) * D_ + dd) * HW_ + i] = __float2bfloat16(v);
                }
            }
        }
    }
}

// ---------------------------------------------------------------- attention
// 1-D grid of 512 blocks, XCD-remapped so all 8 it-tiles of one (h,b) share
// an XCD (K/V panel stays in that XCD's L2). 8 waves/block, each owns 16
// query rows. K/V tiles cooperatively staged in XOR-swizzled LDS with a
// T14 async split (issue loads -> compute -> ds_write after barrier).
__global__ __launch_bounds__(512, 4) void attn_kernel(
    const __hip_bfloat16* __restrict__ q_t, const __hip_bfloat16* __restrict__ k_t,
    const __hip_bfloat16* __restrict__ v_s, __hip_bfloat16* __restrict__ at) {
    const int id  = blockIdx.x;            // 0..511
    const int xcd = id & 7;
    const int q8  = id >> 3;               // 0..63
    const int hb  = xcd * 8 + (q8 >> 3);   // 0..63 : all 8 it-tiles of hb on one XCD
    const int it  = q8 & 7;
    const int h   = hb & 3;
    const int b   = hb >> 2;

    const int t = threadIdx.x;
    const int w  = t >> 6;
    const int lane = t & 63;
    const int l16 = lane & 15, lg = lane >> 4;
    const size_t bh = (size_t)b * NH_ + h;
    const __hip_bfloat16* qp = q_t + bh * HW_ * D_;
    const __hip_bfloat16* kp = k_t + bh * HW_ * D_;
    const __hip_bfloat16* vp = v_s + bh * D_ * HW_;
    const int i0 = it * 128 + w * 16;

    // LDS: swizzled K tile [64 rows][16 slots of 16B], V tile [128 rows][8 slots]
    __shared__ __align__(16) __hip_bfloat16 kbuf[64 * 128];
    __shared__ __align__(16) __hip_bfloat16 vbuf[128 * 64];
    __shared__ __align__(16) __hip_bfloat16 P_lds[8][16][72];

    // phys element index of 16B slot (row, col16) with XOR swizzle
    #define KPHYS(row, c) (((row) * 16 + ((c) ^ ((row) & 7))) * 8)
    #define VPHYS(row, c) (((row) * 8  + ((c) ^ ((row) & 7))) * 8)

    // staging assignment: thread t covers 2 K slots + 2 V slots
    const int krow = t >> 3, kc = t & 7;   // K: 64 rows x col16 {kc, kc+8}
    const int vrow = t >> 2, vc = t & 3;   // V: 128 rows x col16 {vc, vc+4}

    bf16x8 kreg0, kreg1, vreg0, vreg1;
    auto issue_loads = [&](int j0) {
        kreg0 = ld8(kp + (size_t)(j0 + krow) * D_ + kc * 8);
        kreg1 = ld8(kp + (size_t)(j0 + krow) * D_ + (kc + 8) * 8);
        vreg0 = ld8(vp + (size_t)vrow * HW_ + j0 + vc * 8);
        vreg1 = ld8(vp + (size_t)vrow * HW_ + j0 + (vc + 4) * 8);
    };

    bf16x8 aq[4];
    #pragma unroll
    for (int kd = 0; kd < 4; ++kd)
        aq[kd] = ld8(qp + (size_t)(i0 + l16) * D_ + kd * 32 + lg * 8);

    f32x4 accO[8];
    const f32x4 z = {0.f, 0.f, 0.f, 0.f};
    #pragma unroll
    for (int tt = 0; tt < 8; ++tt) accO[tt] = z;
    float mrow[4] = {-INFINITY, -INFINITY, -INFINITY, -INFINITY};
    float lrow[4] = {0.f, 0.f, 0.f, 0.f};

    issue_loads(0);

    for (int jb = 0; jb < 16; ++jb) {
        __syncthreads();   // tile buffer free (all waves done with previous tile)
        *reinterpret_cast<bf16x8*>(&kbuf[KPHYS(krow, kc)])     = kreg0;
        *reinterpret_cast<bf16x8*>(&kbuf[KPHYS(krow, kc + 8)]) = kreg1;
        *reinterpret_cast<bf16x8*>(&vbuf[VPHYS(vrow, vc)])     = vreg0;
        *reinterpret_cast<bf16x8*>(&vbuf[VPHYS(vrow, vc + 4)]) = vreg1;
        __syncthreads();   // tile visible
        if (jb < 15) issue_loads((jb + 1) * 64);  // latency hides under compute

        // ---- QK^T from swizzled LDS
        f32x4 s[4];
        #pragma unroll
        for (int jt = 0; jt < 4; ++jt) s[jt] = z;
        #pragma unroll
        for (int jt = 0; jt < 4; ++jt)
            #pragma unroll
            for (int kd = 0; kd < 4; ++kd) {
                bf16x8 bk = ld8(&kbuf[KPHYS(jt * 16 + l16, kd * 4 + lg)]);
                s[jt] = __builtin_amdgcn_mfma_f32_16x16x32_bf16(aq[kd], bk, s[jt], 0, 0, 0);
            }

        // ---- online softmax (rows in s[jt][r], cols across 16-lane group)
        float p[4][4], alpha[4];
        #pragma unroll
        for (int r = 0; r < 4; ++r) {
            float mx = fmaxf(fmaxf(s[0][r], s[1][r]), fmaxf(s[2][r], s[3][r]));
            #pragma unroll
            for (int off = 1; off < 16; off <<= 1) mx = fmaxf(mx, __shfl_xor(mx, off, 64));
            float mnew = fmaxf(mrow[r], mx);
            alpha[r] = __expf(mrow[r] - mnew);
            mrow[r] = mnew;
            float sm = 0.f;
            #pragma unroll
            for (int jt = 0; jt < 4; ++jt) { p[jt][r] = __expf(s[jt][r] - mnew); sm += p[jt][r]; }
            #pragma unroll
            for (int off = 1; off < 16; off <<= 1) sm += __shfl_xor(sm, off, 64);
            lrow[r] = lrow[r] * alpha[r] + sm;
        }
        {
            const f32x4 a4 = {alpha[0], alpha[1], alpha[2], alpha[3]};
            #pragma unroll
            for (int tt = 0; tt < 8; ++tt) accO[tt] *= a4;
        }

        // ---- P -> wave-private LDS slice (re-layout into A-fragments)
        #pragma unroll
        for (int jt = 0; jt < 4; ++jt)
            #pragma unroll
            for (int r = 0; r < 4; ++r)
                P_lds[w][lg * 4 + r][jt * 16 + l16] = __float2bfloat16(p[jt][r]);

        // ---- PV from swizzled LDS
        #pragma unroll
        for (int ks = 0; ks < 2; ++ks) {
            bf16x8 pa = ld8(&P_lds[w][l16][ks * 32 + lg * 8]);
            #pragma unroll
            for (int dt = 0; dt < 8; ++dt) {
                bf16x8 bv = ld8(&vbuf[VPHYS(dt * 16 + l16, ks * 4 + lg)]);
                accO[dt] = __builtin_amdgcn_mfma_f32_16x16x32_bf16(pa, bv, accO[dt], 0, 0, 0);
            }
        }
    }

    #pragma unroll
    for (int r = 0; r < 4; ++r) {
        float rl = 1.f / lrow[r];
        int i = i0 + lg * 4 + r;
        #pragma unroll
        for (int dt = 0; dt < 8; ++dt)
            at[((size_t)b * HW_ + i) * C_ + h * D_ + dt * 16 + l16] =
                __float2bfloat16(accO[dt][r] * rl);
    }
    #undef KPHYS
    #undef VPHYS
}

// ---------------------------------------------------------------- out GEMM + bias + residual
__global__ __launch_bounds__(256) void out_gemm(
    const __hip_bfloat16* __restrict__ W, const __hip_bfloat16* __restrict__ at,
    const float* __restrict__ b_out, const float* __restrict__ x,
    float* __restrict__ out) {
    const int b = blockIdx.z;
    const int w = threadIdx.x >> 6;
    const int lane = threadIdx.x & 63;
    const int l16 = lane & 15, lg = lane >> 4;
    const int o0 = blockIdx.x * 128 + (w >> 1) * 64;
    const int i0 = blockIdx.y * 128 + (w & 1) * 64;
    const __hip_bfloat16* ab = at + (size_t)b * HW_ * C_;

    f32x4 acc[4][4];
    const f32x4 z = {0.f, 0.f, 0.f, 0.f};
    #pragma unroll
    for (int m = 0; m < 4; ++m)
        #pragma unroll
        for (int n = 0; n < 4; ++n) acc[m][n] = z;

    for (int kk = 0; kk < C_; kk += 32) {
        bf16x8 af[4], bfr[4];
        #pragma unroll
        for (int m = 0; m < 4; ++m)
            af[m] = ld8(W + (size_t)(o0 + m * 16 + l16) * C_ + kk + lg * 8);
        #pragma unroll
        for (int n = 0; n < 4; ++n)
            bfr[n] = ld8(ab + (size_t)(i0 + n * 16 + l16) * C_ + kk + lg * 8);
        #pragma unroll
        for (int m = 0; m < 4; ++m)
            #pragma unroll
            for (int n = 0; n < 4; ++n)
                acc[m][n] = __builtin_amdgcn_mfma_f32_16x16x32_bf16(af[m], bfr[n], acc[m][n], 0, 0, 0);
    }

    #pragma unroll
    for (int m = 0; m < 4; ++m) {
        #pragma unroll
        for (int r = 0; r < 4; ++r) {
            const int o = o0 + m * 16 + lg * 4 + r;
            const float bo = b_out[o];
            #pragma unroll
            for (int n = 0; n < 4; ++n) {
                const int i = i0 + n * 16 + l16;
                const size_t idx = ((size_t)(b * C_ + o)) * HW_ + i;
                out[idx] = acc[m][n][r] + bo + x[idx];
            }
        }
    }
}

// ---------------------------------------------------------------- launch
extern "C" void kernel_launch(void* const* d_in, const int* in_sizes, int n_in,
                              void* d_out, int out_size, void* d_ws, size_t ws_size,
                              hipStream_t stream) {
    (void)in_sizes; (void)n_in; (void)out_size; (void)ws_size;
    const float* x     = (const float*)d_in[0];
    const float* gn_w  = (const float*)d_in[1];
    const float* gn_b  = (const float*)d_in[2];
    const float* w_qkv = (const float*)d_in[3];
    const float* w_out = (const float*)d_in[4];
    const float* b_out = (const float*)d_in[5];
    float* out = (float*)d_out;

    char* ws = (char*)d_ws;
    size_t off = 0;
    auto alloc = [&](size_t bytes) { void* p = ws + off; off += (bytes + 255) & ~255ULL; return p; };
    __hip_bfloat16* wqkv_bf = (__hip_bfloat16*)alloc((size_t)3 * C_ * C_ * 2);
    __hip_bfloat16* wout_bf = (__hip_bfloat16*)alloc((size_t)C_ * C_ * 2);
    __hip_bfloat16* xn_t    = (__hip_bfloat16*)alloc((size_t)B_ * HW_ * C_ * 2);
    __hip_bfloat16* q_t     = (__hip_bfloat16*)alloc((size_t)B_ * HW_ * C_ * 2);
    __hip_bfloat16* k_t     = (__hip_bfloat16*)alloc((size_t)B_ * HW_ * C_ * 2);
    __hip_bfloat16* v_s     = (__hip_bfloat16*)alloc((size_t)B_ * HW_ * C_ * 2);
    __hip_bfloat16* at      = xn_t;  // alias: xn_t dead after qkv_gemm

    convert_w<<<768, 256, 0, stream>>>(w_qkv, w_out, wqkv_bf, wout_bf);
    gn_kernel<<<512, 256, 0, stream>>>(x, gn_w, gn_b, xn_t);
    qkv_gemm<<<dim3(12, 8, 16), 256, 0, stream>>>(wqkv_bf, xn_t, q_t, k_t, v_s);
    attn_kernel<<<512, 512, 0, stream>>>(q_t, k_t, v_s, at);
    out_gemm<<<dim3(4, 8, 16), 256, 0, stream>>>(wout_bf, at, b_out, x, out);
}

// Round 4
// 186.252 us; speedup vs baseline: 2.7097x; 1.4270x over previous
//
#include <hip/hip_runtime.h>
#include <hip/hip_bf16.h>

// Problem constants
#define B_    16
#define C_    512
#define HW_   1024
#define G_    32
#define CPG_  16      // channels per group
#define NH_   4
#define D_    128
#define EPS_  1e-5f
#define SCALE_ 0.08838834764831845f  // 1/sqrt(128)

typedef short bf16x8 __attribute__((ext_vector_type(8)));
typedef short bf16x4 __attribute__((ext_vector_type(4)));
typedef float f32x4  __attribute__((ext_vector_type(4)));

__device__ __forceinline__ bf16x8 ld8(const __hip_bfloat16* p) {
    return *reinterpret_cast<const bf16x8*>(p);
}

// ---------------------------------------------------------------- weights
__global__ __launch_bounds__(256) void convert_w(
    const float* __restrict__ wqkv, const float* __restrict__ wout,
    __hip_bfloat16* __restrict__ wqkv_bf, __hip_bfloat16* __restrict__ wout_bf) {
    const int i = (blockIdx.x * 256 + threadIdx.x) * 4;
    if (i < 3 * C_ * C_) {
        float4 v = *reinterpret_cast<const float4*>(wqkv + i);
        union { bf16x4 s; __hip_bfloat16 h[4]; } u;
        u.h[0] = __float2bfloat16(v.x); u.h[1] = __float2bfloat16(v.y);
        u.h[2] = __float2bfloat16(v.z); u.h[3] = __float2bfloat16(v.w);
        *reinterpret_cast<bf16x4*>(wqkv_bf + i) = u.s;
    }
    if (i < C_ * C_) {
        float4 v = *reinterpret_cast<const float4*>(wout + i);
        union { bf16x4 s; __hip_bfloat16 h[4]; } u;
        u.h[0] = __float2bfloat16(v.x); u.h[1] = __float2bfloat16(v.y);
        u.h[2] = __float2bfloat16(v.z); u.h[3] = __float2bfloat16(v.w);
        *reinterpret_cast<bf16x4*>(wout_bf + i) = u.s;
    }
}

// ---------------------------------------------------------------- groupnorm
__global__ __launch_bounds__(256) void gn_kernel(
    const float* __restrict__ x, const float* __restrict__ gnw,
    const float* __restrict__ gnb, __hip_bfloat16* __restrict__ xn_t) {
    const int b = blockIdx.x >> 5;
    const int g = blockIdx.x & 31;
    const float* xp = x + ((size_t)(b * C_ + g * CPG_)) * HW_;  // 16x1024 contiguous

    float s = 0.f, s2 = 0.f;
    const float4* xv = reinterpret_cast<const float4*>(xp);
    #pragma unroll
    for (int t = 0; t < 16; ++t) {
        float4 v = xv[threadIdx.x + t * 256];
        s  += v.x + v.y + v.z + v.w;
        s2 += v.x * v.x + v.y * v.y + v.z * v.z + v.w * v.w;
    }
    #pragma unroll
    for (int off = 32; off > 0; off >>= 1) {
        s  += __shfl_down(s,  off, 64);
        s2 += __shfl_down(s2, off, 64);
    }
    __shared__ float ss[4], ss2[4];
    if ((threadIdx.x & 63) == 0) { ss[threadIdx.x >> 6] = s; ss2[threadIdx.x >> 6] = s2; }
    __syncthreads();
    s = ss[0] + ss[1] + ss[2] + ss[3];
    s2 = ss2[0] + ss2[1] + ss2[2] + ss2[3];
    const float mean = s * (1.f / 16384.f);
    const float inv  = rsqrtf(fmaxf(s2 * (1.f / 16384.f) - mean * mean, 0.f) + EPS_);

    float a[16], bb[16];
    #pragma unroll
    for (int cc = 0; cc < 16; ++cc) {
        float w = gnw[g * CPG_ + cc];
        a[cc] = inv * w;
        bb[cc] = gnb[g * CPG_ + cc] - mean * inv * w;
    }

    for (int hw = threadIdx.x; hw < HW_; hw += 256) {
        union { bf16x8 v; __hip_bfloat16 h[8]; } u0, u1;
        #pragma unroll
        for (int cc = 0; cc < 8; ++cc)
            u0.h[cc] = __float2bfloat16(xp[cc * HW_ + hw] * a[cc] + bb[cc]);
        #pragma unroll
        for (int cc = 8; cc < 16; ++cc)
            u1.h[cc - 8] = __float2bfloat16(xp[cc * HW_ + hw] * a[cc] + bb[cc]);
        __hip_bfloat16* dst = xn_t + ((size_t)(b * HW_ + hw)) * C_ + g * CPG_;
        *reinterpret_cast<bf16x8*>(dst) = u0.v;
        *reinterpret_cast<bf16x8*>(dst + 8) = u1.v;
    }
}

// swizzled phys element offset: 128-row tile, 8 slots (16B) per row
#define PH_(r, s) (((r) * 8 + ((s) ^ ((r) & 7))) * 8)

// ---------------------------------------------------------------- QKV GEMM
// 1-D grid 1536, XCD-chunked so all 12 o-tiles of a (b,i-tile) pair share an
// XCD. 128x128 tile, BK=64, reg-staged swizzled LDS, T14 async split.
// Q/K blocks compute with swapped MFMA operands so stores run along d.
__global__ __launch_bounds__(256, 3) void qkv_gemm(
    const __hip_bfloat16* __restrict__ W, const __hip_bfloat16* __restrict__ xn_t,
    __hip_bfloat16* __restrict__ q_t, __hip_bfloat16* __restrict__ k_t,
    __hip_bfloat16* __restrict__ v_s) {
    const int id   = blockIdx.x;                 // 0..1535
    const int virt = (id & 7) * 192 + (id >> 3); // XCD-chunked remap
    const int ot   = virt % 12;                  // o tile (0-3 Q, 4-7 K, 8-11 V)
    const int rest = virt / 12;
    const int itl  = rest & 7;
    const int b    = rest >> 3;
    const int o0 = ot * 128, i0 = itl * 128;

    const int t = threadIdx.x;
    const int w = t >> 6, lane = t & 63, l16 = lane & 15, lg = lane >> 4;
    const int wr = w >> 1, wc = w & 1;           // wave's 64x64 quadrant
    const __hip_bfloat16* xb = xn_t + (size_t)b * HW_ * C_;

    __shared__ __align__(16) __hip_bfloat16 Ab[128 * 64];
    __shared__ __align__(16) __hip_bfloat16 Bb[128 * 64];

    const int srow = t >> 1;            // staging row 0..127
    const int scol = (t & 1) * 4;       // staging slot base
    bf16x8 areg[4], breg[4];
    auto issue = [&](int kk) {
        #pragma unroll
        for (int s = 0; s < 4; ++s) {
            areg[s] = ld8(W  + (size_t)(o0 + srow) * C_ + kk + (scol + s) * 8);
            breg[s] = ld8(xb + (size_t)(i0 + srow) * C_ + kk + (scol + s) * 8);
        }
    };

    f32x4 acc[4][4];
    const f32x4 z = {0.f, 0.f, 0.f, 0.f};
    #pragma unroll
    for (int m = 0; m < 4; ++m)
        #pragma unroll
        for (int n = 0; n < 4; ++n) acc[m][n] = z;

    issue(0);
    for (int ks = 0; ks < 8; ++ks) {
        __syncthreads();   // buffer free
        #pragma unroll
        for (int s = 0; s < 4; ++s) {
            *reinterpret_cast<bf16x8*>(&Ab[PH_(srow, scol + s)]) = areg[s];
            *reinterpret_cast<bf16x8*>(&Bb[PH_(srow, scol + s)]) = breg[s];
        }
        __syncthreads();   // tile visible
        if (ks < 7) issue((ks + 1) * 64);

        if (ot < 8) {  // Q/K: swapped operands -> col(l16) = o-dim
            #pragma unroll
            for (int kks = 0; kks < 2; ++kks) {
                bf16x8 af[4], bfr[4];
                #pragma unroll
                for (int m = 0; m < 4; ++m)
                    af[m] = ld8(&Ab[PH_(wr * 64 + m * 16 + l16, kks * 4 + lg)]);
                #pragma unroll
                for (int n = 0; n < 4; ++n)
                    bfr[n] = ld8(&Bb[PH_(wc * 64 + n * 16 + l16, kks * 4 + lg)]);
                #pragma unroll
                for (int m = 0; m < 4; ++m)
                    #pragma unroll
                    for (int n = 0; n < 4; ++n)
                        acc[m][n] = __builtin_amdgcn_mfma_f32_16x16x32_bf16(bfr[n], af[m], acc[m][n], 0, 0, 0);
            }
        } else {       // V: normal order -> col(l16) = i-dim
            #pragma unroll
            for (int kks = 0; kks < 2; ++kks) {
                bf16x8 af[4], bfr[4];
                #pragma unroll
                for (int m = 0; m < 4; ++m)
                    af[m] = ld8(&Ab[PH_(wr * 64 + m * 16 + l16, kks * 4 + lg)]);
                #pragma unroll
                for (int n = 0; n < 4; ++n)
                    bfr[n] = ld8(&Bb[PH_(wc * 64 + n * 16 + l16, kks * 4 + lg)]);
                #pragma unroll
                for (int m = 0; m < 4; ++m)
                    #pragma unroll
                    for (int n = 0; n < 4; ++n)
                        acc[m][n] = __builtin_amdgcn_mfma_f32_16x16x32_bf16(af[m], bfr[n], acc[m][n], 0, 0, 0);
            }
        }
    }

    if (ot < 4) {            // Q (pre-scaled): row(reg)=i, col(l16)=d
        const int hd = ot;
        __hip_bfloat16* base = q_t + (size_t)(b * NH_ + hd) * HW_ * D_;
        const int dd = wr * 64 + l16;
        #pragma unroll
        for (int m = 0; m < 4; ++m)
            #pragma unroll
            for (int n = 0; n < 4; ++n)
                #pragma unroll
                for (int r = 0; r < 4; ++r) {
                    const int i = i0 + wc * 64 + n * 16 + lg * 4 + r;
                    base[(size_t)i * D_ + dd + m * 16] = __float2bfloat16(acc[m][n][r] * SCALE_);
                }
    } else if (ot < 8) {     // K
        const int hd = ot - 4;
        __hip_bfloat16* base = k_t + (size_t)(b * NH_ + hd) * HW_ * D_;
        const int dd = wr * 64 + l16;
        #pragma unroll
        for (int m = 0; m < 4; ++m)
            #pragma unroll
            for (int n = 0; n < 4; ++n)
                #pragma unroll
                for (int r = 0; r < 4; ++r) {
                    const int i = i0 + wc * 64 + n * 16 + lg * 4 + r;
                    base[(size_t)i * D_ + dd + m * 16] = __float2bfloat16(acc[m][n][r]);
                }
    } else {                 // V: row(reg)=d, col(l16)=i
        const int hd = ot - 8;
        __hip_bfloat16* base = v_s + (size_t)(b * NH_ + hd) * D_ * HW_;
        #pragma unroll
        for (int m = 0; m < 4; ++m)
            #pragma unroll
            for (int r = 0; r < 4; ++r) {
                const int dd = wr * 64 + m * 16 + lg * 4 + r;
                #pragma unroll
                for (int n = 0; n < 4; ++n) {
                    const int i = i0 + wc * 64 + n * 16 + l16;
                    base[(size_t)dd * HW_ + i] = __float2bfloat16(acc[m][n][r]);
                }
            }
    }
}

// ---------------------------------------------------------------- attention
__global__ __launch_bounds__(512, 4) void attn_kernel(
    const __hip_bfloat16* __restrict__ q_t, const __hip_bfloat16* __restrict__ k_t,
    const __hip_bfloat16* __restrict__ v_s, __hip_bfloat16* __restrict__ at) {
    const int id  = blockIdx.x;            // 0..511
    const int xcd = id & 7;
    const int q8  = id >> 3;               // 0..63
    const int hb  = xcd * 8 + (q8 >> 3);   // all 8 it-tiles of hb on one XCD
    const int it  = q8 & 7;
    const int h   = hb & 3;
    const int b   = hb >> 2;

    const int t = threadIdx.x;
    const int w  = t >> 6;
    const int lane = t & 63;
    const int l16 = lane & 15, lg = lane >> 4;
    const size_t bh = (size_t)b * NH_ + h;
    const __hip_bfloat16* qp = q_t + bh * HW_ * D_;
    const __hip_bfloat16* kp = k_t + bh * HW_ * D_;
    const __hip_bfloat16* vp = v_s + bh * D_ * HW_;
    const int i0 = it * 128 + w * 16;

    __shared__ __align__(16) __hip_bfloat16 kbuf[64 * 128];
    __shared__ __align__(16) __hip_bfloat16 vbuf[128 * 64];
    __shared__ __align__(16) __hip_bfloat16 P_lds[8][16][72];

    #define KPHYS(row, c) (((row) * 16 + ((c) ^ ((row) & 7))) * 8)
    #define VPHYS(row, c) (((row) * 8  + ((c) ^ ((row) & 7))) * 8)

    const int krow = t >> 3, kc = t & 7;
    const int vrow = t >> 2, vc = t & 3;

    bf16x8 kreg0, kreg1, vreg0, vreg1;
    auto issue_loads = [&](int j0) {
        kreg0 = ld8(kp + (size_t)(j0 + krow) * D_ + kc * 8);
        kreg1 = ld8(kp + (size_t)(j0 + krow) * D_ + (kc + 8) * 8);
        vreg0 = ld8(vp + (size_t)vrow * HW_ + j0 + vc * 8);
        vreg1 = ld8(vp + (size_t)vrow * HW_ + j0 + (vc + 4) * 8);
    };

    bf16x8 aq[4];
    #pragma unroll
    for (int kd = 0; kd < 4; ++kd)
        aq[kd] = ld8(qp + (size_t)(i0 + l16) * D_ + kd * 32 + lg * 8);

    f32x4 accO[8];
    const f32x4 z = {0.f, 0.f, 0.f, 0.f};
    #pragma unroll
    for (int tt = 0; tt < 8; ++tt) accO[tt] = z;
    float mrow[4] = {-INFINITY, -INFINITY, -INFINITY, -INFINITY};
    float lrow[4] = {0.f, 0.f, 0.f, 0.f};

    issue_loads(0);

    for (int jb = 0; jb < 16; ++jb) {
        __syncthreads();
        *reinterpret_cast<bf16x8*>(&kbuf[KPHYS(krow, kc)])     = kreg0;
        *reinterpret_cast<bf16x8*>(&kbuf[KPHYS(krow, kc + 8)]) = kreg1;
        *reinterpret_cast<bf16x8*>(&vbuf[VPHYS(vrow, vc)])     = vreg0;
        *reinterpret_cast<bf16x8*>(&vbuf[VPHYS(vrow, vc + 4)]) = vreg1;
        __syncthreads();
        if (jb < 15) issue_loads((jb + 1) * 64);

        f32x4 s[4];
        #pragma unroll
        for (int jt = 0; jt < 4; ++jt) s[jt] = z;
        #pragma unroll
        for (int jt = 0; jt < 4; ++jt)
            #pragma unroll
            for (int kd = 0; kd < 4; ++kd) {
                bf16x8 bk = ld8(&kbuf[KPHYS(jt * 16 + l16, kd * 4 + lg)]);
                s[jt] = __builtin_amdgcn_mfma_f32_16x16x32_bf16(aq[kd], bk, s[jt], 0, 0, 0);
            }

        float p[4][4], alpha[4];
        #pragma unroll
        for (int r = 0; r < 4; ++r) {
            float mx = fmaxf(fmaxf(s[0][r], s[1][r]), fmaxf(s[2][r], s[3][r]));
            #pragma unroll
            for (int off = 1; off < 16; off <<= 1) mx = fmaxf(mx, __shfl_xor(mx, off, 64));
            float mnew = fmaxf(mrow[r], mx);
            alpha[r] = __expf(mrow[r] - mnew);
            mrow[r] = mnew;
            float sm = 0.f;
            #pragma unroll
            for (int jt = 0; jt < 4; ++jt) { p[jt][r] = __expf(s[jt][r] - mnew); sm += p[jt][r]; }
            #pragma unroll
            for (int off = 1; off < 16; off <<= 1) sm += __shfl_xor(sm, off, 64);
            lrow[r] = lrow[r] * alpha[r] + sm;
        }
        {
            const f32x4 a4 = {alpha[0], alpha[1], alpha[2], alpha[3]};
            #pragma unroll
            for (int tt = 0; tt < 8; ++tt) accO[tt] *= a4;
        }

        #pragma unroll
        for (int jt = 0; jt < 4; ++jt)
            #pragma unroll
            for (int r = 0; r < 4; ++r)
                P_lds[w][lg * 4 + r][jt * 16 + l16] = __float2bfloat16(p[jt][r]);

        #pragma unroll
        for (int ks = 0; ks < 2; ++ks) {
            bf16x8 pa = ld8(&P_lds[w][l16][ks * 32 + lg * 8]);
            #pragma unroll
            for (int dt = 0; dt < 8; ++dt) {
                bf16x8 bv = ld8(&vbuf[VPHYS(dt * 16 + l16, ks * 4 + lg)]);
                accO[dt] = __builtin_amdgcn_mfma_f32_16x16x32_bf16(pa, bv, accO[dt], 0, 0, 0);
            }
        }
    }

    #pragma unroll
    for (int r = 0; r < 4; ++r) {
        float rl = 1.f / lrow[r];
        int i = i0 + lg * 4 + r;
        #pragma unroll
        for (int dt = 0; dt < 8; ++dt)
            at[((size_t)b * HW_ + i) * C_ + h * D_ + dt * 16 + l16] =
                __float2bfloat16(accO[dt][r] * rl);
    }
    #undef KPHYS
    #undef VPHYS
}

// ---------------------------------------------------------------- out GEMM + bias + residual
// 1-D grid 512, XCD-chunked; same LDS-staged structure as qkv_gemm.
__global__ __launch_bounds__(256, 3) void out_gemm(
    const __hip_bfloat16* __restrict__ W, const __hip_bfloat16* __restrict__ at,
    const float* __restrict__ b_out, const float* __restrict__ x,
    float* __restrict__ out) {
    const int id   = blockIdx.x;                // 0..511
    const int virt = (id & 7) * 64 + (id >> 3); // XCD-chunked remap
    const int ot   = virt & 3;
    const int rest = virt >> 2;
    const int itl  = rest & 7;
    const int b    = rest >> 3;
    const int o0 = ot * 128, i0 = itl * 128;

    const int t = threadIdx.x;
    const int w = t >> 6, lane = t & 63, l16 = lane & 15, lg = lane >> 4;
    const int wr = w >> 1, wc = w & 1;
    const __hip_bfloat16* ab = at + (size_t)b * HW_ * C_;

    __shared__ __align__(16) __hip_bfloat16 Ab[128 * 64];
    __shared__ __align__(16) __hip_bfloat16 Bb[128 * 64];

    const int srow = t >> 1;
    const int scol = (t & 1) * 4;
    bf16x8 areg[4], breg[4];
    auto issue = [&](int kk) {
        #pragma unroll
        for (int s = 0; s < 4; ++s) {
            areg[s] = ld8(W  + (size_t)(o0 + srow) * C_ + kk + (scol + s) * 8);
            breg[s] = ld8(ab + (size_t)(i0 + srow) * C_ + kk + (scol + s) * 8);
        }
    };

    f32x4 acc[4][4];
    const f32x4 z = {0.f, 0.f, 0.f, 0.f};
    #pragma unroll
    for (int m = 0; m < 4; ++m)
        #pragma unroll
        for (int n = 0; n < 4; ++n) acc[m][n] = z;

    issue(0);
    for (int ks = 0; ks < 8; ++ks) {
        __syncthreads();
        #pragma unroll
        for (int s = 0; s < 4; ++s) {
            *reinterpret_cast<bf16x8*>(&Ab[PH_(srow, scol + s)]) = areg[s];
            *reinterpret_cast<bf16x8*>(&Bb[PH_(srow, scol + s)]) = breg[s];
        }
        __syncthreads();
        if (ks < 7) issue((ks + 1) * 64);

        #pragma unroll
        for (int kks = 0; kks < 2; ++kks) {
            bf16x8 af[4], bfr[4];
            #pragma unroll
            for (int m = 0; m < 4; ++m)
                af[m] = ld8(&Ab[PH_(wr * 64 + m * 16 + l16, kks * 4 + lg)]);
            #pragma unroll
            for (int n = 0; n < 4; ++n)
                bfr[n] = ld8(&Bb[PH_(wc * 64 + n * 16 + l16, kks * 4 + lg)]);
            #pragma unroll
            for (int m = 0; m < 4; ++m)
                #pragma unroll
                for (int n = 0; n < 4; ++n)
                    acc[m][n] = __builtin_amdgcn_mfma_f32_16x16x32_bf16(af[m], bfr[n], acc[m][n], 0, 0, 0);
        }
    }

    #pragma unroll
    for (int m = 0; m < 4; ++m)
        #pragma unroll
        for (int r = 0; r < 4; ++r) {
            const int o = o0 + wr * 64 + m * 16 + lg * 4 + r;
            const float bo = b_out[o];
            #pragma unroll
            for (int n = 0; n < 4; ++n) {
                const int i = i0 + wc * 64 + n * 16 + l16;
                const size_t idx = ((size_t)(b * C_ + o)) * HW_ + i;
                out[idx] = acc[m][n][r] + bo + x[idx];
            }
        }
}

// ---------------------------------------------------------------- launch
extern "C" void kernel_launch(void* const* d_in, const int* in_sizes, int n_in,
                              void* d_out, int out_size, void* d_ws, size_t ws_size,
                              hipStream_t stream) {
    (void)in_sizes; (void)n_in; (void)out_size; (void)ws_size;
    const float* x     = (const float*)d_in[0];
    const float* gn_w  = (const float*)d_in[1];
    const float* gn_b  = (const float*)d_in[2];
    const float* w_qkv = (const float*)d_in[3];
    const float* w_out = (const float*)d_in[4];
    const float* b_out = (const float*)d_in[5];
    float* out = (float*)d_out;

    char* ws = (char*)d_ws;
    size_t off = 0;
    auto alloc = [&](size_t bytes) { void* p = ws + off; off += (bytes + 255) & ~255ULL; return p; };
    __hip_bfloat16* wqkv_bf = (__hip_bfloat16*)alloc((size_t)3 * C_ * C_ * 2);
    __hip_bfloat16* wout_bf = (__hip_bfloat16*)alloc((size_t)C_ * C_ * 2);
    __hip_bfloat16* xn_t    = (__hip_bfloat16*)alloc((size_t)B_ * HW_ * C_ * 2);
    __hip_bfloat16* q_t     = (__hip_bfloat16*)alloc((size_t)B_ * HW_ * C_ * 2);
    __hip_bfloat16* k_t     = (__hip_bfloat16*)alloc((size_t)B_ * HW_ * C_ * 2);
    __hip_bfloat16* v_s     = (__hip_bfloat16*)alloc((size_t)B_ * HW_ * C_ * 2);
    __hip_bfloat16* at      = xn_t;  // alias: xn_t dead after qkv_gemm

    convert_w<<<768, 256, 0, stream>>>(w_qkv, w_out, wqkv_bf, wout_bf);
    gn_kernel<<<512, 256, 0, stream>>>(x, gn_w, gn_b, xn_t);
    qkv_gemm<<<1536, 256, 0, stream>>>(wqkv_bf, xn_t, q_t, k_t, v_s);
    attn_kernel<<<512, 512, 0, stream>>>(q_t, k_t, v_s, at);
    out_gemm<<<512, 256, 0, stream>>>(wout_bf, at, b_out, x, out);
}